// Round 8
// baseline (252.283 us; speedup 1.0000x reference)
//
#include <hip/hip_runtime.h>

typedef unsigned char  u8;
typedef unsigned short u16;
typedef unsigned int   u32;
typedef unsigned long long u64;
typedef __attribute__((ext_vector_type(8))) short bf16x8;
typedef __attribute__((ext_vector_type(4))) float f32x4;

#define NOBS 128
#define NN   1280
#define NH   256
#define NO   80
#define TT   5
#define RR   16          // batch rows per block
#define NTHR 512         // 8 waves/block, 2 col-tiles per wave
#define BP1  88          // layer1 bits LDS pitch (u16)
#define BP2  20          // layer2/3 bits pitch (u16)

#define VMW8()  asm volatile("s_waitcnt vmcnt(8)" ::: "memory")
#define VMW4()  asm volatile("s_waitcnt vmcnt(4)" ::: "memory")
#define VMW0()  asm volatile("s_waitcnt vmcnt(0)" ::: "memory")
#define FENCE() asm volatile("" ::: "memory")

// Inline near-correctly-rounded f32 exp via f64 degree-11 Taylor.
__device__ __forceinline__ float exp_cr(float arg) {
  double xa = (double)arg;
  double nd = __builtin_rint(xa * 1.4426950408889634074);
  double r  = fma(nd, -6.93147180369123816490e-01, xa);
  r         = fma(nd, -1.90821492927058770002e-10, r);
  double p = 2.50521083854417187751e-08;
  p = fma(p, r, 2.75573192239858906526e-07);
  p = fma(p, r, 2.75573192239858906526e-06);
  p = fma(p, r, 2.48015873015873015873e-05);
  p = fma(p, r, 1.98412698412698412698e-04);
  p = fma(p, r, 1.38888888888888888889e-03);
  p = fma(p, r, 8.33333333333333333333e-03);
  p = fma(p, r, 4.16666666666666666667e-02);
  p = fma(p, r, 1.66666666666666666667e-01);
  p = fma(p, r, 0.5);
  p = fma(p, r, 1.0);
  p = fma(p, r, 1.0);
  int n = (int)nd;
  union { u64 u; double d; } s;
  s.u = ((u64)(u32)(n + 1023)) << 52;
  return (n < -150) ? 0.f : (float)(s.d * p);
}

// DMA one 32-row x 32-col f32 weight tile (4KB) into LDS: 4 instructions.
// lane_src = W + row(lane>>1)*ld + kbase + (lane&1)*4, so instr i covers
// bytes [i*32, i*32+32) of every row; LDS layout becomes
// tile[row][kbyte] = lds[(kbyte>>5)*1024 + row*32 + (kbyte&31)].
__device__ __forceinline__ void dma4(const float* __restrict__ lane_src, u16* dst) {
  __builtin_amdgcn_global_load_lds((const u32*)lane_src,        (u32*)dst,          16, 0, 0);
  __builtin_amdgcn_global_load_lds((const u32*)(lane_src + 8),  (u32*)(dst + 512),  16, 0, 0);
  __builtin_amdgcn_global_load_lds((const u32*)(lane_src + 16), (u32*)(dst + 1024), 16, 0, 0);
  __builtin_amdgcn_global_load_lds((const u32*)(lane_src + 24), (u32*)(dst + 1536), 16, 0, 0);
}

// In-register 3-way bf16 split of 8 f32 (bit-identical to the old prep's
// split3: same RNE formula, same exact subtractions):
//   t = bits + 0x7FFF + ((bits>>16)&1);  hi = t>>16;  hi_f = t & 0xFFFF0000.
__device__ __forceinline__ void split8(f32x4 va, f32x4 vb,
                                       bf16x8* H, bf16x8* M, bf16x8* L) {
  union { f32x4 v; float f[4]; } A, B; A.v = va; B.v = vb;
  union { u32 u[4]; bf16x8 v; } h, m, l;
  #pragma unroll
  for (int p = 0; p < 4; ++p) {
    float w0 = (p < 2) ? A.f[2 * p]     : B.f[2 * (p - 2)];
    float w1 = (p < 2) ? A.f[2 * p + 1] : B.f[2 * (p - 2) + 1];
    u32 x0 = __float_as_uint(w0);
    u32 t0 = x0 + 0x7FFFu + ((x0 >> 16) & 1u);
    float r10 = __fsub_rn(w0, __uint_as_float(t0 & 0xFFFF0000u));   // exact
    u32 y0 = __float_as_uint(r10);
    u32 s0 = y0 + 0x7FFFu + ((y0 >> 16) & 1u);
    float r20 = __fsub_rn(r10, __uint_as_float(s0 & 0xFFFF0000u));  // exact
    u32 z0 = __float_as_uint(r20);
    u32 g0 = (z0 + 0x7FFFu + ((z0 >> 16) & 1u)) >> 16;
    u32 x1 = __float_as_uint(w1);
    u32 t1 = x1 + 0x7FFFu + ((x1 >> 16) & 1u);
    float r11 = __fsub_rn(w1, __uint_as_float(t1 & 0xFFFF0000u));
    u32 y1 = __float_as_uint(r11);
    u32 s1 = y1 + 0x7FFFu + ((y1 >> 16) & 1u);
    float r21 = __fsub_rn(r11, __uint_as_float(s1 & 0xFFFF0000u));
    u32 z1 = __float_as_uint(r21);
    u32 g1 = (z1 + 0x7FFFu + ((z1 >> 16) & 1u)) >> 16;
    h.u[p] = (t0 >> 16) | (t1 & 0xFFFF0000u);
    m.u[p] = (s0 >> 16) | (s1 & 0xFFFF0000u);
    l.u[p] = g0 | (g1 << 16);
  }
  *H = h.v; *M = m.v; *L = l.v;
}

// A-fragment: 8 spike bits x 5 t -> bf16 0/1 fragments via 16-entry LDS LUT.
__device__ __forceinline__ void build_afr(
    const u16* lbits, int bpitch, int kc, int ks, int m16, int sh,
    const u64* __restrict__ lut, bf16x8 afr[TT])
{
  #pragma unroll
  for (int t = 0; t < TT; ++t) {
    u32 bwv = *(const u32*)(lbits + (t * RR + m16) * bpitch + kc * 4 + ks * 2);
    u32 b = (bwv >> sh) & 0xFFu;
    union { u64 d[2]; bf16x8 v; } x;
    x.d[0] = lut[b & 15u];
    x.d[1] = lut[b >> 4];
    afr[t] = x.v;
  }
}

// Raw-f32 staged GEMM (R8): no pre-split workspace at all. Per kcks, the
// wave DMAs its own 32 rows x 32 k-cols f32 tile (triple-buffered, 2-tile
// lookahead), ds_reads its two 8-f32 row fragments, splits them to
// hi/mid/lo bf16 in-register (bit-identical values to the old prep), and
// runs the same 3x10 MFMA sequence. Per-output accumulation order
// kc:(ks0:hi,mid,lo),(ks1:hi,mid,lo) — unchanged from all prior rounds.
// vmcnt discipline (4 loads/tile): issue T(k+2) -> outstanding 12 -> VMW8
// waits T(k) landed; tail VMW4 / VMW0 (R16 race rule, one level deeper).
__device__ __forceinline__ void gemm_raw(
    const u16* lbits, int bpitch,
    const float* __restrict__ lane_base,   // W + rowclamped*ld + (lane&1)*4
    int nkc, u16* mybuf, const u64* __restrict__ lut,
    int lane, f32x4 acc[2][TT])
{
  const int m16 = lane & 15, q = lane >> 4;
  const int ro0 = q * 512 + m16 * 16;      // u16 off: row m16, k-group q
  const int ro1 = ro0 + 256;               // row m16+16
  const int sh = q * 8;
  const int nst = nkc * 2;
  const float* nsrc = lane_base + 64;      // tile 2 (tiles stride 32 f32)

  // Prologue DMAs for tiles 0,1 were issued by the caller.
  for (int kcks = 0; kcks < nst; ++kcks) {
    const int kc = kcks >> 1, ks = kcks & 1;
    if (kcks + 2 < nst) {                  // WAR-safe: buf (kcks+2)%3 was
      dma4(nsrc, mybuf + ((kcks + 2) % 3) * 2048);   // consumed at kcks-1
      nsrc += 32;
    }
    FENCE();
    if (kcks + 2 < nst) { VMW8(); } else if (kcks + 1 < nst) { VMW4(); } else { VMW0(); }
    const u16* cb = mybuf + (kcks % 3) * 2048;
    f32x4 a0 = *(const f32x4*)(cb + ro0);
    f32x4 a1 = *(const f32x4*)(cb + ro0 + 8);
    f32x4 b0 = *(const f32x4*)(cb + ro1);
    f32x4 b1 = *(const f32x4*)(cb + ro1 + 8);
    FENCE();
    bf16x8 H0, M0, L0, H1, M1, L1;
    split8(a0, a1, &H0, &M0, &L0);
    split8(b0, b1, &H1, &M1, &L1);
    bf16x8 afr[TT];
    build_afr(lbits, bpitch, kc, ks, m16, sh, lut, afr);
    #pragma unroll
    for (int t = 0; t < TT; ++t)
      acc[0][t] = __builtin_amdgcn_mfma_f32_16x16x32_bf16(afr[t], H0, acc[0][t], 0, 0, 0);
    #pragma unroll
    for (int t = 0; t < TT; ++t)
      acc[1][t] = __builtin_amdgcn_mfma_f32_16x16x32_bf16(afr[t], H1, acc[1][t], 0, 0, 0);
    #pragma unroll
    for (int t = 0; t < TT; ++t)
      acc[0][t] = __builtin_amdgcn_mfma_f32_16x16x32_bf16(afr[t], M0, acc[0][t], 0, 0, 0);
    #pragma unroll
    for (int t = 0; t < TT; ++t)
      acc[1][t] = __builtin_amdgcn_mfma_f32_16x16x32_bf16(afr[t], M1, acc[1][t], 0, 0, 0);
    #pragma unroll
    for (int t = 0; t < TT; ++t)
      acc[0][t] = __builtin_amdgcn_mfma_f32_16x16x32_bf16(afr[t], L0, acc[0][t], 0, 0, 0);
    #pragma unroll
    for (int t = 0; t < TT; ++t)
      acc[1][t] = __builtin_amdgcn_mfma_f32_16x16x32_bf16(afr[t], L1, acc[1][t], 0, 0, 0);
    FENCE();
  }
}

// Prologue: issue tiles 0,1 (8 loads) so they fly under unrelated compute.
__device__ __forceinline__ void gemm_pro(const float* __restrict__ lane_base,
                                         u16* mybuf) {
  dma4(lane_base, mybuf);
  dma4(lane_base + 32, mybuf + 2048);
  FENCE();
}

// LIF recurrence over t; emit spike bits via ballot. 2 col-tiles per wave.
__device__ __forceinline__ void recur_spikes2(
    f32x4 acc[2][TT], const float* __restrict__ bias,
    int lane, int wv, u16* sbits, int spitch)
{
  const int q = lane >> 4, m16 = lane & 15;
  #pragma unroll
  for (int i = 0; i < 2; ++i) {
    int ct = wv * 2 + i;
    int j = ct * 16 + m16;
    float bj = bias[j];
    #pragma unroll
    for (int rg = 0; rg < 4; ++rg) {
      float c = 0.f, v = 0.f, sprev = 0.f;
      #pragma unroll
      for (int t = 0; t < TT; ++t) {
        float u = acc[i][t][rg];
        c = __fadd_rn(__fadd_rn(__fmul_rn(c, 0.5f), u), bj);       // (c*0.5 + u) + b
        float vd = __fmul_rn(v, 0.75f);
        v = __fadd_rn((sprev > 0.5f) ? 0.f : vd, c);               // v*0.75*(1-s) + c
        bool sp = v > 0.5f;
        u64 mask = __ballot(sp);
        if (m16 == 0) {
          int row = q * 4 + rg;
          sbits[(t * RR + row) * spitch + ct] = (u16)(mask >> (q * 16));
        }
        sprev = sp ? 1.f : 0.f;
      }
    }
  }
}

// Single dispatch: encoder -> 3-layer SNN (raw-f32 staged GEMM with
// in-register split) -> decoder. 124KB LDS -> 1 block/CU; each CU runs its
// 2 blocks sequentially. No workspace, no second kernel, no cross-block
// communication.
__global__ __launch_bounds__(NTHR, 2) void snn_one(
    const float* __restrict__ obs, const float* __restrict__ enc_mean,
    const float* __restrict__ enc_std,
    const float* __restrict__ W1, const float* __restrict__ W2,
    const float* __restrict__ Wo,
    const float* __restrict__ b1, const float* __restrict__ b2, const float* __restrict__ bo,
    const float* __restrict__ dec_w, const float* __restrict__ dec_b, const float* __restrict__ log_std,
    float* __restrict__ out, int Btot)
{
  __shared__ __align__(16) u16 smem[61984];          // 123,968 B -> 1 block/CU
  u16* bufs = smem;                                  // [8 waves][3][2048] f32 tiles
  u16* encb = smem + 49152;                          // [5t*16r][BP1] = 7040
  u16* s1b  = smem + 56192;                          // [5t*16r][BP2] = 1600
  u16* s2b  = smem + 57792;                          // 1600
  float* soacc = (float*)(smem + 59392);             // [16][80] f32
  u64* lutp = (u64*)(smem + 61952);                  // 16 x 8B nibble LUT

  const int tid  = threadIdx.x;
  const int lane = tid & 63;
  const int wv   = tid >> 6;          // 0..7
  const int r0   = blockIdx.x * RR;
  u16* mybuf = bufs + wv * 6144;

  const int j0 = wv * 32 + (lane >> 1);              // this lane's DMA row
  const float* lb1 = W1 + j0 * 1280 + (lane & 1) * 4;

  // ---------- L1 prologue DMAs: in flight across the whole encoder ---------
  gemm_pro(lb1, mybuf);

  // ---------- nibble->bf16x4 LUT (bit-identical to the ALU expansion) ------
  if (tid < 16) {
    u32 lo32 = (((tid & 3u) * 0x8001u) & 0x10001u) * 0x3F80u;
    u32 hi32 = ((((tid >> 2) & 3u) * 0x8001u) & 0x10001u) * 0x3F80u;
    lutp[tid] = (u64)lo32 | ((u64)hi32 << 32);
  }

  // ---------- fused population encoder: 16 rows x 1280 cols -> bit-planes --
  // 2560 half-items of 8 exps, exactly 5 per thread; bit-identical per-k
  // arithmetic to the original encoder.
  for (int h = tid; h < RR * 160; h += NTHR) {
    int r = h / 160, rem = h - r * 160;
    int w = rem >> 1, hi = rem & 1;
    const float* obsrow = obs + (r0 + r) * NOBS;
    u32 bits[TT] = {0, 0, 0, 0, 0};
    #pragma unroll
    for (int e = 0; e < 8; ++e) {
      int k = w * 16 + hi * 8 + e;
      int f = k / 10;
      float x  = obsrow[f];
      float m  = enc_mean[k];
      float sd = enc_std[k];
      float d  = __fsub_rn(x, m);
      float arg = __fdiv_rn(__fmul_rn(-0.5f, __fmul_rn(d, d)), __fmul_rn(sd, sd));
      float a = exp_cr(arg);
      float v = 0.f;
      #pragma unroll
      for (int t = 0; t < TT; ++t) {
        v = __fadd_rn(v, a);
        if (v > 0.999f) { bits[t] |= (1u << e); v = __fsub_rn(v, 0.999f); }
      }
    }
    u8* eb = (u8*)encb;
    #pragma unroll
    for (int t = 0; t < TT; ++t)
      eb[((t * RR + r) * BP1 + w) * 2 + hi] = (u8)bits[t];
  }
  __syncthreads();                                   // encb + LUT ready

  f32x4 acc[2][TT];
  const f32x4 zero4 = {0.f, 0.f, 0.f, 0.f};
#define ZERO_ACC() { _Pragma("unroll") for (int i = 0; i < 2; ++i) \
                     _Pragma("unroll") for (int t = 0; t < TT; ++t) acc[i][t] = zero4; }

  // ---------- layer 1: [80 x 1280] @ [1280 x 256] (3-way split fused) ------
  ZERO_ACC();
  gemm_raw(encb, BP1, lb1, 20, mybuf, lutp, lane, acc);
  const float* lb2 = W2 + j0 * 256 + (lane & 1) * 4;
  gemm_pro(lb2, mybuf);                              // L2 prologue
  recur_spikes2(acc, b1, lane, wv, s1b, BP2);
  __syncthreads();

  // ---------- layer 2: [80 x 256] @ [256 x 256] ----------------------------
  ZERO_ACC();
  gemm_raw(s1b, BP2, lb2, 4, mybuf, lutp, lane, acc);
  const int jc = (j0 < NO) ? j0 : (NO - 1);          // clamp: rows >=80 give
  const float* lb3 = Wo + jc * 256 + (lane & 1) * 4; // garbage, discarded
  if (wv < 3) gemm_pro(lb3, mybuf);                  // L3 prologue
  recur_spikes2(acc, b2, lane, wv, s2b, BP2);
  __syncthreads();

  // ---------- layer 3: [80 x 256] @ [256 x 80(+pad cols)] — waves 0..2 -----
  if (wv < 3) {
    ZERO_ACC();
    gemm_raw(s2b, BP2, lb3, 4, mybuf, lutp, lane, acc);
    const int q = lane >> 4, m16 = lane & 15;
    #pragma unroll
    for (int i = 0; i < 2; ++i) {
      int j = (wv * 2 + i) * 16 + m16;
      bool valid = j < NO;
      float bj = valid ? bo[j] : 0.f;
      #pragma unroll
      for (int rg = 0; rg < 4; ++rg) {
        float c = 0.f, v = 0.f, sprev = 0.f;
        int cnt = 0;
        #pragma unroll
        for (int t = 0; t < TT; ++t) {
          float u = acc[i][t][rg];
          c = __fadd_rn(__fadd_rn(__fmul_rn(c, 0.5f), u), bj);
          float vd = __fmul_rn(v, 0.75f);
          v = __fadd_rn((sprev > 0.5f) ? 0.f : vd, c);
          bool sp = v > 0.5f;
          cnt += sp ? 1 : 0;
          sprev = sp ? 1.f : 0.f;
        }
        if (valid) soacc[(q * 4 + rg) * NO + j] = __fdiv_rn((float)cnt, 5.0f);
      }
    }
  }
  __syncthreads();

  // ---------- decoder: grouped dot + ELU -----------------------------------
  if (tid < RR * 8) {
    int r = tid >> 3, a = tid & 7;
    float s = 0.f;
    const float* so = soacc + r * NO + a * 10;
    #pragma unroll
    for (int p = 0; p < 10; ++p)
      s = __fadd_rn(s, __fmul_rn(so[p], dec_w[a * 10 + p]));
    s = __fadd_rn(s, dec_b[a]);
    float mu = (s > 0.f) ? s : expm1f(s);
    out[(r0 + r) * 8 + a] = mu;
  }
  if (blockIdx.x == 0 && tid < 8) {
    out[Btot * 8 + tid] = expf(log_std[tid]);
  }
}

extern "C" void kernel_launch(void* const* d_in, const int* in_sizes, int n_in,
                              void* d_out, int out_size, void* d_ws, size_t ws_size,
                              hipStream_t stream) {
  const float* obs      = (const float*)d_in[0];
  const float* enc_mean = (const float*)d_in[1];
  const float* enc_std  = (const float*)d_in[2];
  const float* W1       = (const float*)d_in[3];
  const float* b1       = (const float*)d_in[4];
  const float* W2       = (const float*)d_in[5];
  const float* b2       = (const float*)d_in[6];
  const float* Wo       = (const float*)d_in[7];
  const float* bo       = (const float*)d_in[8];
  const float* dec_w    = (const float*)d_in[9];
  const float* dec_b    = (const float*)d_in[10];
  const float* log_std  = (const float*)d_in[11];
  float* out = (float*)d_out;
  int B = in_sizes[0] / NOBS;   // 8192

  hipLaunchKernelGGL(snn_one, dim3(B / RR), dim3(NTHR), 0, stream,
                     obs, enc_mean, enc_std, W1, W2, Wo,
                     b1, b2, bo, dec_w, dec_b, log_std, out, B);
}

// Round 9
// 157.122 us; speedup vs baseline: 1.6056x; 1.6056x over previous
//
#include <hip/hip_runtime.h>

typedef unsigned char  u8;
typedef unsigned short u16;
typedef unsigned int   u32;
typedef unsigned long long u64;
typedef __attribute__((ext_vector_type(8))) short bf16x8;
typedef __attribute__((ext_vector_type(4))) float f32x4;

#define NOBS 128
#define NN   1280
#define NH   256
#define NO   80
#define TT   5
#define RR   16          // batch rows per block
#define NTHR 512         // 8 waves/block, 2 col-tiles per wave
#define BP1  88          // layer1 bits LDS pitch (u16)
#define BP2  20          // layer2/3 bits pitch (u16)

// ws layout (u16 units), stage-contiguous: [kc][ks][sel][rows][32], rows
// XOR-swizzled within (sub-fragment s of row j stored at s ^ ((j>>1)&3)).
// W1s [20][2][3][256][32] @0 ; W2s [4][2][3][256][32] @983040 ;
// Wos [4][2][3][128][32] @1179648 (pad128)
#define W1TOT   983040
#define W2S_OFF 983040
#define WOS_OFF 1179648
#define WS_TOTAL 1277952

#define PREP_BLOCKS 208           // 53248 threads, 24 ws items each

__device__ __forceinline__ float bf2f(u16 u) {
  union { u32 i; float f; } x; x.i = ((u32)u) << 16; return x.f;
}
__device__ __forceinline__ u16 f2bf(float f) {
  union { float f; u32 i; } x; x.f = f;
  u32 i = x.i + 0x7FFFu + ((x.i >> 16) & 1u);   // RNE
  return (u16)(i >> 16);
}

// Inline near-correctly-rounded f32 exp via f64 degree-11 Taylor.
__device__ __forceinline__ float exp_cr(float arg) {
  double xa = (double)arg;
  double nd = __builtin_rint(xa * 1.4426950408889634074);
  double r  = fma(nd, -6.93147180369123816490e-01, xa);
  r         = fma(nd, -1.90821492927058770002e-10, r);
  double p = 2.50521083854417187751e-08;
  p = fma(p, r, 2.75573192239858906526e-07);
  p = fma(p, r, 2.75573192239858906526e-06);
  p = fma(p, r, 2.48015873015873015873e-05);
  p = fma(p, r, 1.98412698412698412698e-04);
  p = fma(p, r, 1.38888888888888888889e-03);
  p = fma(p, r, 8.33333333333333333333e-03);
  p = fma(p, r, 4.16666666666666666667e-02);
  p = fma(p, r, 1.66666666666666666667e-01);
  p = fma(p, r, 0.5);
  p = fma(p, r, 1.0);
  p = fma(p, r, 1.0);
  int n = (int)nd;
  union { u64 u; double d; } s;
  s.u = ((u64)(u32)(n + 1023)) << 52;
  return (n < -150) ? 0.f : (float)(s.d * p);
}

// Weight-split prep, vectorized (R5, hand-verified vs scalar mapping): each
// thread owns 8 contiguous source cols of one row and emits all 3 sel
// planes — 2 float4 loads, 8 hi/mid/lo splits, 3 coalesced 16B stores.
// Same split arithmetic and same swizzled storage positions as the original
// scalar prep -> bit-identical ws.
__global__ __launch_bounds__(256) void prep_w(
    const float* __restrict__ W1, const float* __restrict__ W2,
    const float* __restrict__ Wo, u16* __restrict__ ws)
{
  const int T = blockIdx.x * 256 + threadIdx.x;     // < 53248 exactly
  const float* src;
  int dstb, selstep;
  bool pad = false;
  if (T < 40960) {                                  // W1 [256][1280]
    int kcks = T >> 10, r = T & 1023;
    int kc = kcks >> 1, ks = kcks & 1, j = r >> 2, kgrp = r & 3;
    int kk0 = (kgrp ^ ((j >> 1) & 3)) << 3;
    src = W1 + j * 1280 + kc * 64 + ks * 32 + kk0;
    dstb = kc * 49152 + ks * 24576 + j * 32 + kgrp * 8;
    selstep = 8192;
  } else if (T < 49152) {                           // W2 [256][256]
    int T2 = T - 40960;
    int kcks = T2 >> 10, r = T2 & 1023;
    int kc = kcks >> 1, ks = kcks & 1, j = r >> 2, kgrp = r & 3;
    int kk0 = (kgrp ^ ((j >> 1) & 3)) << 3;
    src = W2 + j * 256 + kc * 64 + ks * 32 + kk0;
    dstb = W2S_OFF + kc * 49152 + ks * 24576 + j * 32 + kgrp * 8;
    selstep = 8192;
  } else {                                          // Wo [80][256] pad to 128
    int T3 = T - 49152;
    int kcks = T3 >> 9, r = T3 & 511;
    int kc = kcks >> 1, ks = kcks & 1, j = r >> 2, kgrp = r & 3;
    int kk0 = (kgrp ^ ((j >> 1) & 3)) << 3;
    src = Wo + j * 256 + kc * 64 + ks * 32 + kk0;
    dstb = WOS_OFF + kc * 24576 + ks * 12288 + j * 32 + kgrp * 8;
    selstep = 4096;
    pad = (j >= NO);
  }
  float w[8];
  if (!pad) {
    float4 w0 = *(const float4*)src;          // 32B-aligned
    float4 w1 = *(const float4*)(src + 4);
    w[0] = w0.x; w[1] = w0.y; w[2] = w0.z; w[3] = w0.w;
    w[4] = w1.x; w[5] = w1.y; w[6] = w1.z; w[7] = w1.w;
  } else {
    #pragma unroll
    for (int e = 0; e < 8; ++e) w[e] = 0.f;
  }
  union { u16 u[8]; uint4 q; } hi, mid, lo;
  #pragma unroll
  for (int e = 0; e < 8; ++e) {
    u16 h = f2bf(w[e]);
    float r1 = __fsub_rn(w[e], bf2f(h));      // exact
    u16 m = f2bf(r1);
    float r2 = __fsub_rn(r1, bf2f(m));        // exact
    hi.u[e] = h; mid.u[e] = m; lo.u[e] = f2bf(r2);
  }
  *(uint4*)(ws + dstb)               = hi.q;
  *(uint4*)(ws + dstb + selstep)     = mid.q;
  *(uint4*)(ws + dstb + 2 * selstep) = lo.q;
}

// A-fragment: 8 spike bits x 5 t -> bf16 0/1 fragments via 16-entry LDS LUT.
// Entry n lives on banks 2n/2n+1 (all 16 disjoint); same-entry reads
// broadcast -> conflict-free. Values bit-identical to the ALU expansion.
__device__ __forceinline__ void build_afr(
    const u16* lbits, int bpitch, int kc, int ks, int m16, int sh,
    const u64* __restrict__ lut, bf16x8 afr[TT])
{
  #pragma unroll
  for (int t = 0; t < TT; ++t) {
    u32 bwv = *(const u32*)(lbits + (t * RR + m16) * bpitch + kc * 4 + ks * 2);
    u32 b = (bwv >> sh) & 0xFFu;
    union { u64 d[2]; bf16x8 v; } x;
    x.d[0] = lut[b & 15u];
    x.d[1] = lut[b >> 4];
    afr[t] = x.v;
  }
}

// Direct-to-register GEMM (R9): each wave's 2KB stage slice is wave-PRIVATE
// (its own 32 output cols) — no cross-wave reuse — so the LDS round-trip
// (global_load_lds + vmcnt discipline + ds_read latency + bank conflicts)
// bought nothing. Each lane now loads its two bf16x8 B-fragments straight
// from ws (same bytes, same swizzled addresses -> coalesced within the 2KB
// slice), 2-stage register prefetch (2 parity slots). No inline-asm waits:
// the compiler sees the full dep graph and inserts counted vmcnt itself.
// MFMA sequence and per-output accumulation order
// kc:(ks0:hi,mid,lo),(ks1:hi,mid,lo) — bit-identical to all prior rounds.
__device__ __forceinline__ void gemm_reg(
    const u16* lbits, int bpitch,
    const u16* __restrict__ wsbase, int nkc, int selblk,
    const u64* __restrict__ lut, int wv, int lane, f32x4 acc[2][TT])
{
  const int m16 = lane & 15, q = lane >> 4;
  const int swz = (q ^ ((m16 >> 1) & 3)) * 8;
  const int sh = q * 8;
  const int nst = nkc * 6;
  const u16* lb = wsbase + wv * 1024 + m16 * 32 + swz;   // per-lane base

  // Prefetch slots by stage parity (stage st = (kc*2+ks)*3+sel).
  bf16x8 e0a = *(const bf16x8*)(lb);                 // st 0 (even slot)
  bf16x8 e0b = *(const bf16x8*)(lb + 512);
  bf16x8 o1a = *(const bf16x8*)(lb + selblk);        // st 1 (odd slot)
  bf16x8 o1b = *(const bf16x8*)(lb + selblk + 512);
  const u16* nsrc = lb + 2 * selblk;                 // source for st+2
  int st = 0;

  for (int kc = 0; kc < nkc; ++kc) {
    #pragma unroll
    for (int ks = 0; ks < 2; ++ks) {
      bf16x8 afr[TT];
      build_afr(lbits, bpitch, kc, ks, m16, sh, lut, afr);
      #pragma unroll
      for (int sel = 0; sel < 3; ++sel, ++st) {
        const bool even = (((3 * ks + sel) & 1) == 0);   // static after unroll
        const bf16x8 ca = even ? e0a : o1a;
        const bf16x8 cb = even ? e0b : o1b;
        #pragma unroll
        for (int t = 0; t < TT; ++t)
          acc[0][t] = __builtin_amdgcn_mfma_f32_16x16x32_bf16(afr[t], ca, acc[0][t], 0, 0, 0);
        #pragma unroll
        for (int t = 0; t < TT; ++t)
          acc[1][t] = __builtin_amdgcn_mfma_f32_16x16x32_bf16(afr[t], cb, acc[1][t], 0, 0, 0);
        if (st + 2 < nst) {                // refill this parity's slot (st+2)
          bf16x8 na = *(const bf16x8*)(nsrc);
          bf16x8 nb = *(const bf16x8*)(nsrc + 512);
          if (even) { e0a = na; e0b = nb; } else { o1a = na; o1b = nb; }
          nsrc += selblk;
        }
      }
    }
  }
}

// LIF recurrence over t; emit spike bits via ballot. 2 col-tiles per wave.
__device__ __forceinline__ void recur_spikes2(
    f32x4 acc[2][TT], const float* __restrict__ bias,
    int lane, int wv, u16* sbits, int spitch)
{
  const int q = lane >> 4, m16 = lane & 15;
  #pragma unroll
  for (int i = 0; i < 2; ++i) {
    int ct = wv * 2 + i;
    int j = ct * 16 + m16;
    float bj = bias[j];
    #pragma unroll
    for (int rg = 0; rg < 4; ++rg) {
      float c = 0.f, v = 0.f, sprev = 0.f;
      #pragma unroll
      for (int t = 0; t < TT; ++t) {
        float u = acc[i][t][rg];
        c = __fadd_rn(__fadd_rn(__fmul_rn(c, 0.5f), u), bj);       // (c*0.5 + u) + b
        float vd = __fmul_rn(v, 0.75f);
        v = __fadd_rn((sprev > 0.5f) ? 0.f : vd, c);               // v*0.75*(1-s) + c
        bool sp = v > 0.5f;
        u64 mask = __ballot(sp);
        if (m16 == 0) {
          int row = q * 4 + rg;
          sbits[(t * RR + row) * spitch + ct] = (u16)(mask >> (q * 16));
        }
        sprev = sp ? 1.f : 0.f;
      }
    }
  }
}

__global__ __launch_bounds__(NTHR, 4) void snn_main(
    const float* __restrict__ obs, const float* __restrict__ enc_mean,
    const float* __restrict__ enc_std,
    const float* __restrict__ b1, const float* __restrict__ b2, const float* __restrict__ bo,
    const float* __restrict__ dec_w, const float* __restrict__ dec_b, const float* __restrict__ log_std,
    const u16* __restrict__ wsW, float* __restrict__ out, int Btot)
{
  __shared__ __align__(16) u16 smem[12864];          // 25,728 B (no staging bufs)
  u16* encb = smem;                                  // [5t*16r][BP1] = 7040
  u16* s1b  = smem + 7040;                           // [5t*16r][BP2] = 1600
  u16* s2b  = smem + 8640;                           // 1600
  float* soacc = (float*)(smem + 10240);             // [16][80] f32 = 2560 u16
  u64* lutp = (u64*)(smem + 12800);                  // 16 x 8B nibble LUT

  const int tid  = threadIdx.x;
  const int lane = tid & 63;
  const int wv   = tid >> 6;          // 0..7
  const int r0   = blockIdx.x * RR;

  // ---------- nibble->bf16x4 LUT (bit-identical to the ALU expansion) ------
  if (tid < 16) {
    u32 lo32 = (((tid & 3u) * 0x8001u) & 0x10001u) * 0x3F80u;
    u32 hi32 = ((((tid >> 2) & 3u) * 0x8001u) & 0x10001u) * 0x3F80u;
    lutp[tid] = (u64)lo32 | ((u64)hi32 << 32);
  }

  // ---------- fused population encoder: 16 rows x 1280 cols -> bit-planes --
  // 2560 half-items of 8 exps, exactly 5 per thread; bit-identical per-k
  // arithmetic to the original encoder.
  for (int h = tid; h < RR * 160; h += NTHR) {
    int r = h / 160, rem = h - r * 160;
    int w = rem >> 1, hi = rem & 1;
    const float* obsrow = obs + (r0 + r) * NOBS;
    u32 bits[TT] = {0, 0, 0, 0, 0};
    #pragma unroll
    for (int e = 0; e < 8; ++e) {
      int k = w * 16 + hi * 8 + e;
      int f = k / 10;
      float x  = obsrow[f];
      float m  = enc_mean[k];
      float sd = enc_std[k];
      float d  = __fsub_rn(x, m);
      float arg = __fdiv_rn(__fmul_rn(-0.5f, __fmul_rn(d, d)), __fmul_rn(sd, sd));
      float a = exp_cr(arg);
      float v = 0.f;
      #pragma unroll
      for (int t = 0; t < TT; ++t) {
        v = __fadd_rn(v, a);
        if (v > 0.999f) { bits[t] |= (1u << e); v = __fsub_rn(v, 0.999f); }
      }
    }
    u8* eb = (u8*)encb;
    #pragma unroll
    for (int t = 0; t < TT; ++t)
      eb[((t * RR + r) * BP1 + w) * 2 + hi] = (u8)bits[t];
  }
  __syncthreads();                                   // encb + LUT ready

  f32x4 acc[2][TT];
  const f32x4 zero4 = {0.f, 0.f, 0.f, 0.f};
#define ZERO_ACC() { _Pragma("unroll") for (int i = 0; i < 2; ++i) \
                     _Pragma("unroll") for (int t = 0; t < TT; ++t) acc[i][t] = zero4; }

  // ---------- layer 1: [80 x 1280] @ [1280 x 256] (3-way split fused) ------
  ZERO_ACC();
  gemm_reg(encb, BP1, wsW, 20, 8192, lutp, wv, lane, acc);
  recur_spikes2(acc, b1, lane, wv, s1b, BP2);
  __syncthreads();

  // ---------- layer 2: [80 x 256] @ [256 x 256] ----------------------------
  ZERO_ACC();
  gemm_reg(s1b, BP2, wsW + W2S_OFF, 4, 8192, lutp, wv, lane, acc);
  recur_spikes2(acc, b2, lane, wv, s2b, BP2);
  __syncthreads();

  // ---------- layer 3: [80 x 256] @ [256 x 80(pad)] — waves 0..2 -----------
  if (wv < 3) {
    ZERO_ACC();
    gemm_reg(s2b, BP2, wsW + WOS_OFF, 4, 4096, lutp, wv, lane, acc);
    const int q = lane >> 4, m16 = lane & 15;
    #pragma unroll
    for (int i = 0; i < 2; ++i) {
      int j = (wv * 2 + i) * 16 + m16;
      bool valid = j < NO;
      float bj = valid ? bo[j] : 0.f;
      #pragma unroll
      for (int rg = 0; rg < 4; ++rg) {
        float c = 0.f, v = 0.f, sprev = 0.f;
        int cnt = 0;
        #pragma unroll
        for (int t = 0; t < TT; ++t) {
          float u = acc[i][t][rg];
          c = __fadd_rn(__fadd_rn(__fmul_rn(c, 0.5f), u), bj);
          float vd = __fmul_rn(v, 0.75f);
          v = __fadd_rn((sprev > 0.5f) ? 0.f : vd, c);
          bool sp = v > 0.5f;
          cnt += sp ? 1 : 0;
          sprev = sp ? 1.f : 0.f;
        }
        if (valid) soacc[(q * 4 + rg) * NO + j] = __fdiv_rn((float)cnt, 5.0f);
      }
    }
  }
  __syncthreads();

  // ---------- decoder: grouped dot + ELU -----------------------------------
  if (tid < RR * 8) {
    int r = tid >> 3, a = tid & 7;
    float s = 0.f;
    const float* so = soacc + r * NO + a * 10;
    #pragma unroll
    for (int p = 0; p < 10; ++p)
      s = __fadd_rn(s, __fmul_rn(so[p], dec_w[a * 10 + p]));
    s = __fadd_rn(s, dec_b[a]);
    float mu = (s > 0.f) ? s : expm1f(s);
    out[(r0 + r) * 8 + a] = mu;
  }
  if (blockIdx.x == 0 && tid < 8) {
    out[Btot * 8 + tid] = expf(log_std[tid]);
  }
}

extern "C" void kernel_launch(void* const* d_in, const int* in_sizes, int n_in,
                              void* d_out, int out_size, void* d_ws, size_t ws_size,
                              hipStream_t stream) {
  const float* obs      = (const float*)d_in[0];
  const float* enc_mean = (const float*)d_in[1];
  const float* enc_std  = (const float*)d_in[2];
  const float* W1       = (const float*)d_in[3];
  const float* b1       = (const float*)d_in[4];
  const float* W2       = (const float*)d_in[5];
  const float* b2       = (const float*)d_in[6];
  const float* Wo       = (const float*)d_in[7];
  const float* bo       = (const float*)d_in[8];
  const float* dec_w    = (const float*)d_in[9];
  const float* dec_b    = (const float*)d_in[10];
  const float* log_std  = (const float*)d_in[11];
  u16*   ws  = (u16*)d_ws;
  float* out = (float*)d_out;
  int B = in_sizes[0] / NOBS;   // 8192

  hipLaunchKernelGGL(prep_w, dim3(PREP_BLOCKS), dim3(256), 0, stream,
                     W1, W2, Wo, ws);
  hipLaunchKernelGGL(snn_main, dim3(B / RR), dim3(NTHR), 0, stream,
                     obs, enc_mean, enc_std, b1, b2, bo, dec_w, dec_b, log_std,
                     ws, out, B);
}